// Round 3
// baseline (258.585 us; speedup 1.0000x reference)
//
#include <hip/hip_runtime.h>

#define IPB 10        // items per block (250 of 256 lanes active)
#define NT 256
#define NQ 25
#define KVD 9
#define QSCALE 0.4808983469629878f      /* log2(e)/3 : folds 1/sqrt(9) and exp->exp2 */
#define MSCALE (-1.4426950408889634e9f) /* -1e9 * log2(e) */

// FMA 8 preloaded floats against q[0..7]
__device__ __forceinline__ float dot8v(float4 a, float4 b,
                                       const float* __restrict__ q, float acc) {
  acc = fmaf(a.x, q[0], acc);
  acc = fmaf(a.y, q[1], acc);
  acc = fmaf(a.z, q[2], acc);
  acc = fmaf(a.w, q[3], acc);
  acc = fmaf(b.x, q[4], acc);
  acc = fmaf(b.y, q[5], acc);
  acc = fmaf(b.z, q[6], acc);
  acc = fmaf(b.w, q[7], acc);
  return acc;
}

__device__ __forceinline__ float dot8(const float* __restrict__ w,
                                      const float* __restrict__ xv, float acc) {
  float4 a = *(const float4*)(w);
  float4 b = *(const float4*)(w + 4);
  return dot8v(a, b, xv, acc);
}

// 9-dim projection: out[e] = bias[e] + sum_d W[e][d]*xv[d], W split as 8+1
__device__ __forceinline__ void proj9(const float* __restrict__ w8,
                                      const float* __restrict__ w9,
                                      const float* __restrict__ bias,
                                      const float* __restrict__ xv,
                                      float* __restrict__ outv) {
  float4 na = *(const float4*)(w9);
  float4 nb = *(const float4*)(w9 + 4);
  float  nc = w9[8];
  float4 ba = *(const float4*)(bias);
  float4 bb = *(const float4*)(bias + 4);
  float  bc = bias[8];
  const float w9e[9]  = {na.x, na.y, na.z, na.w, nb.x, nb.y, nb.z, nb.w, nc};
  const float seed[9] = {ba.x, ba.y, ba.z, ba.w, bb.x, bb.y, bb.z, bb.w, bc};
#pragma unroll
  for (int e = 0; e < KVD; ++e)
    outv[e] = dot8(w8 + e * 8, xv, fmaf(w9e[e], xv[8], seed[e]));
}

// r1 shape: 23 KB LDS, 4-wave blocks (more small blocks beats wide barriers; r2
// showed 8-wave/4-block config costs +15% stall at equal VALU busy-cycles).
// launch_bounds(256,6): VGPR cap 85 == the 6-waves/SIMD boundary; we now WANT
// ~80 live regs for 4-row LDS load batches (r1's 36-reg allocation serialized
// the ds_read->fma chains and exposed LDS latency).
__global__ __launch_bounds__(NT, 6) void attn_fused(
    const float* __restrict__ x, const float* __restrict__ mask,
    const float* __restrict__ Wq, const float* __restrict__ bq,
    const float* __restrict__ Wk, const float* __restrict__ bk,
    const float* __restrict__ Wv, const float* __restrict__ bv,
    const float* __restrict__ gamma, const float* __restrict__ beta,
    float* __restrict__ out, int B) {
  __shared__ __align__(16) float sW8[3][4][KVD][8];   // 3456 B
  __shared__ __align__(16) float sW9[3][4][12];       //  576 B
  __shared__ __align__(16) float sBias[3][4][12];     //  576 B
  __shared__ __align__(16) float sK8[IPB][NQ][8];     // 8000 B
  __shared__ __align__(16) float sK9[IPB][28];        // 1120 B
  __shared__ __align__(16) float sV8[IPB][NQ][8];     // 8000 B
  __shared__ __align__(16) float sV9[IPB][28];        // 1120 B

  const int tid = threadIdx.x;
  const int il = tid / NQ;
  const int tk = tid - il * NQ;
  const long item = (long)blockIdx.x * IPB + il;
  const bool active = (tid < IPB * NQ) && (item < (long)B);

  // ---- prefetch x before staging: HBM latency hides behind weight staging ----
  float xv[KVD];
  if (active) {
    const float* xp = x + item * 225 + tk * KVD;
#pragma unroll
    for (int d = 0; d < KVD; ++d) xv[d] = xp[d];
  }

  // ---- stage parameters (q pre-scaled by log2e/3) ----
  for (int i = tid; i < 324; i += NT) {  // 4*9*9
    int g = i / 81;
    int r = i - g * 81;
    int e = r / 9;
    int d = r - e * 9;
    float a = Wq[i] * QSCALE, b = Wk[i], c = Wv[i];
    if (d < 8) {
      sW8[0][g][e][d] = a; sW8[1][g][e][d] = b; sW8[2][g][e][d] = c;
    } else {
      sW9[0][g][e] = a; sW9[1][g][e] = b; sW9[2][g][e] = c;
    }
  }
  for (int i = tid; i < 36; i += NT) {
    int g = i / 9, d = i - g * 9;
    sBias[0][g][d] = bq[i] * QSCALE;
    sBias[1][g][d] = bk[i];
    sBias[2][g][d] = bv[i];
  }
  __syncthreads();

  const int g = (tk < 3) ? 0 : (tk < 13) ? 1 : (tk < 23) ? 2 : 3;
  if (active) {
    // k and v share one temp; q computed after the barrier (short live ranges)
    float t[KVD];
    proj9(&sW8[1][g][0][0], &sW9[1][g][0], &sBias[1][g][0], xv, t);
    *(float4*)&sK8[il][tk][0] = make_float4(t[0], t[1], t[2], t[3]);
    *(float4*)&sK8[il][tk][4] = make_float4(t[4], t[5], t[6], t[7]);
    sK9[il][tk] = t[8];
    proj9(&sW8[2][g][0][0], &sW9[2][g][0], &sBias[2][g][0], xv, t);
    *(float4*)&sV8[il][tk][0] = make_float4(t[0], t[1], t[2], t[3]);
    *(float4*)&sV8[il][tk][4] = make_float4(t[4], t[5], t[6], t[7]);
    sV9[il][tk] = t[8];
  }
  __syncthreads();

  if (active) {
    float q[KVD];
    proj9(&sW8[0][g][0][0], &sW9[0][g][0], &sBias[0][g][0], xv, q);
    const float q8 = q[8];

    const float* kb = &sK8[il][0][0];
    const float* k9 = &sK9[il][0];
    const float* vb = &sV8[il][0][0];
    const float* v9 = &sV9[il][0];

    // ---- scores: 6 batches of 4 K-rows; 9 ds_reads issued ahead of 33 FMAs
    // (mask[j] is a wave-uniform s_load; *MSCALE is one v_mul per j)
    float s[NQ];
#pragma unroll
    for (int c = 0; c < 6; ++c) {
      const float* kp = kb + c * 32;
      float4 r0a = *(const float4*)(kp);
      float4 r0b = *(const float4*)(kp + 4);
      float4 r1a = *(const float4*)(kp + 8);
      float4 r1b = *(const float4*)(kp + 12);
      float4 r2a = *(const float4*)(kp + 16);
      float4 r2b = *(const float4*)(kp + 20);
      float4 r3a = *(const float4*)(kp + 24);
      float4 r3b = *(const float4*)(kp + 28);
      float4 k9c = *(const float4*)(k9 + 4 * c);
      s[4*c+0] = dot8v(r0a, r0b, q, fmaf(q8, k9c.x, mask[4*c+0] * MSCALE));
      s[4*c+1] = dot8v(r1a, r1b, q, fmaf(q8, k9c.y, mask[4*c+1] * MSCALE));
      s[4*c+2] = dot8v(r2a, r2b, q, fmaf(q8, k9c.z, mask[4*c+2] * MSCALE));
      s[4*c+3] = dot8v(r3a, r3b, q, fmaf(q8, k9c.w, mask[4*c+3] * MSCALE));
    }
    {
      float4 ta = *(const float4*)(kb + 192);
      float4 tb = *(const float4*)(kb + 196);
      s[24] = dot8v(ta, tb, q, fmaf(q8, k9[24], mask[24] * MSCALE));
    }

    // ---- max: v_max3-friendly tree, dep depth 3
    float t0 = fmaxf(fmaxf(s[0], s[1]), s[2]);
    float t1 = fmaxf(fmaxf(s[3], s[4]), s[5]);
    float t2 = fmaxf(fmaxf(s[6], s[7]), s[8]);
    float t3 = fmaxf(fmaxf(s[9], s[10]), s[11]);
    float t4 = fmaxf(fmaxf(s[12], s[13]), s[14]);
    float t5 = fmaxf(fmaxf(s[15], s[16]), s[17]);
    float t6 = fmaxf(fmaxf(s[18], s[19]), s[20]);
    float t7 = fmaxf(fmaxf(s[21], s[22]), s[23]);
    float u0 = fmaxf(fmaxf(t0, t1), t2);
    float u1 = fmaxf(fmaxf(t3, t4), t5);
    float u2 = fmaxf(fmaxf(t6, t7), s[24]);
    const float m = fmaxf(fmaxf(u0, u1), u2);

    // ---- fused exp2 + PV + denominator, 6 batches of 4 V-rows.
    // exp2 runs on the TRANS pipe while the batch's 9 ds_reads are in flight;
    // s[] dies 4 per batch; normalization deferred (inv folded into residual).
    float o[KVD];
#pragma unroll
    for (int d = 0; d < KVD; ++d) o[d] = 0.f;
    float a0 = 0.f, a1 = 0.f, a2 = 0.f, a3 = 0.f;
#pragma unroll
    for (int c = 0; c < 6; ++c) {
      const float* vp = vb + c * 32;
      float4 v0a = *(const float4*)(vp);
      float4 v0b = *(const float4*)(vp + 4);
      float4 v1a = *(const float4*)(vp + 8);
      float4 v1b = *(const float4*)(vp + 12);
      float4 v2a = *(const float4*)(vp + 16);
      float4 v2b = *(const float4*)(vp + 20);
      float4 v3a = *(const float4*)(vp + 24);
      float4 v3b = *(const float4*)(vp + 28);
      float4 v9c = *(const float4*)(v9 + 4 * c);
      float p0 = __builtin_amdgcn_exp2f(s[4*c+0] - m);
      float p1 = __builtin_amdgcn_exp2f(s[4*c+1] - m);
      float p2 = __builtin_amdgcn_exp2f(s[4*c+2] - m);
      float p3 = __builtin_amdgcn_exp2f(s[4*c+3] - m);
      a0 += p0; a1 += p1; a2 += p2; a3 += p3;
      o[0] = fmaf(p0, v0a.x, o[0]); o[1] = fmaf(p0, v0a.y, o[1]);
      o[2] = fmaf(p0, v0a.z, o[2]); o[3] = fmaf(p0, v0a.w, o[3]);
      o[4] = fmaf(p0, v0b.x, o[4]); o[5] = fmaf(p0, v0b.y, o[5]);
      o[6] = fmaf(p0, v0b.z, o[6]); o[7] = fmaf(p0, v0b.w, o[7]);
      o[8] = fmaf(p0, v9c.x, o[8]);
      o[0] = fmaf(p1, v1a.x, o[0]); o[1] = fmaf(p1, v1a.y, o[1]);
      o[2] = fmaf(p1, v1a.z, o[2]); o[3] = fmaf(p1, v1a.w, o[3]);
      o[4] = fmaf(p1, v1b.x, o[4]); o[5] = fmaf(p1, v1b.y, o[5]);
      o[6] = fmaf(p1, v1b.z, o[6]); o[7] = fmaf(p1, v1b.w, o[7]);
      o[8] = fmaf(p1, v9c.y, o[8]);
      o[0] = fmaf(p2, v2a.x, o[0]); o[1] = fmaf(p2, v2a.y, o[1]);
      o[2] = fmaf(p2, v2a.z, o[2]); o[3] = fmaf(p2, v2a.w, o[3]);
      o[4] = fmaf(p2, v2b.x, o[4]); o[5] = fmaf(p2, v2b.y, o[5]);
      o[6] = fmaf(p2, v2b.z, o[6]); o[7] = fmaf(p2, v2b.w, o[7]);
      o[8] = fmaf(p2, v9c.z, o[8]);
      o[0] = fmaf(p3, v3a.x, o[0]); o[1] = fmaf(p3, v3a.y, o[1]);
      o[2] = fmaf(p3, v3a.z, o[2]); o[3] = fmaf(p3, v3a.w, o[3]);
      o[4] = fmaf(p3, v3b.x, o[4]); o[5] = fmaf(p3, v3b.y, o[5]);
      o[6] = fmaf(p3, v3b.z, o[6]); o[7] = fmaf(p3, v3b.w, o[7]);
      o[8] = fmaf(p3, v9c.w, o[8]);
    }
    {
      float4 ta = *(const float4*)(vb + 192);
      float4 tb = *(const float4*)(vb + 196);
      float p24 = __builtin_amdgcn_exp2f(s[24] - m);
      a0 += p24;
      o[0] = fmaf(p24, ta.x, o[0]); o[1] = fmaf(p24, ta.y, o[1]);
      o[2] = fmaf(p24, ta.z, o[2]); o[3] = fmaf(p24, ta.w, o[3]);
      o[4] = fmaf(p24, tb.x, o[4]); o[5] = fmaf(p24, tb.y, o[5]);
      o[6] = fmaf(p24, tb.z, o[6]); o[7] = fmaf(p24, tb.w, o[7]);
      o[8] = fmaf(p24, v9[24], o[8]);
    }
    const float sum = (a0 + a1) + (a2 + a3);
    const float inv = __builtin_amdgcn_rcpf(sum);

    // ---- residual + one-pass LayerNorm (inv folded into the residual fmaf)
    float r[KVD];
    float sm = 0.f, sq = 0.f;
#pragma unroll
    for (int d = 0; d < KVD; ++d) {
      r[d] = fmaf(o[d], inv, xv[d]);
      sm += r[d];
      sq = fmaf(r[d], r[d], sq);
    }
    const float mu = sm * (1.0f / 9.0f);
    float var = fmaf(mu, -mu, sq * (1.0f / 9.0f));
    const float rs = __builtin_amdgcn_rsqf(var + 1e-5f);
    float* op = out + item * 225 + tk * KVD;
    // gamma/beta: wave-uniform s_loads, no LDS staging needed
#pragma unroll
    for (int d = 0; d < KVD; ++d)
      op[d] = fmaf((r[d] - mu) * rs, gamma[d], beta[d]);
  }
}

extern "C" void kernel_launch(void* const* d_in, const int* in_sizes, int n_in,
                              void* d_out, int out_size, void* d_ws, size_t ws_size,
                              hipStream_t stream) {
  const float* x     = (const float*)d_in[0];
  const float* mask  = (const float*)d_in[1];
  const float* Wq    = (const float*)d_in[2];
  const float* bq    = (const float*)d_in[3];
  const float* Wk    = (const float*)d_in[4];
  const float* bk    = (const float*)d_in[5];
  const float* Wv    = (const float*)d_in[6];
  const float* bv    = (const float*)d_in[7];
  const float* gamma = (const float*)d_in[8];
  const float* beta  = (const float*)d_in[9];
  float* out = (float*)d_out;
  const int B = in_sizes[0] / 225;
  const int grid = (B + IPB - 1) / IPB;
  attn_fused<<<grid, NT, 0, stream>>>(x, mask, Wq, bq, Wk, bk, Wv, bv,
                                      gamma, beta, out, B);
}

// Round 5
// 237.365 us; speedup vs baseline: 1.0894x; 1.0894x over previous
//
#include <hip/hip_runtime.h>

typedef __fp16 h2 __attribute__((ext_vector_type(2)));       // what cvt_pkrtz returns
typedef _Float16 f16x2 __attribute__((ext_vector_type(2)));  // what fdot2 expects

#define IPB 10        // items per block (250 of 256 lanes active)
#define NT 256
#define NQ 25
#define KVD 9
#define QSCALE 0.4808983469629878f      /* log2(e)/3 : folds 1/sqrt(9) and exp->exp2 */
#define MSCALE (-1.4426950408889634e9f) /* -1e9 * log2(e) */

// v_dot2_f32_f16: 2 f16 MACs per slot, f32 accumulate (2x f32-FMA rate on CDNA)
__device__ __forceinline__ float fdot2(h2 a, h2 b, float c) {
  return __builtin_amdgcn_fdot2(__builtin_bit_cast(f16x2, a),
                                __builtin_bit_cast(f16x2, b), c, false);
}
__device__ __forceinline__ h2 pk(float lo, float hi) {
  return __builtin_amdgcn_cvt_pkrtz(lo, hi);
}

// 9-dim projection in f16-dot2: row = 10 halves (pairs d01,d23,d45,d67,d8+zero),
// padded to 16 halves for b128-aligned rows. 5 fdot2 per output element.
__device__ __forceinline__ void proj9h(const __fp16* __restrict__ w,
                                       const float* __restrict__ bias,
                                       const h2* __restrict__ xh,
                                       float* __restrict__ outv) {
#pragma unroll
  for (int e = 0; e < KVD; ++e) {
    const h2* wr = (const h2*)(w + e * 16);
    float acc = bias[e];
#pragma unroll
    for (int t = 0; t < 5; ++t) acc = fdot2(wr[t], xh[t], acc);
    outv[e] = acc;
  }
}

// LDS ~17.9 KB -> 8 blocks/CU x 4 waves = 32 waves/CU (100% cap) while keeping
// the proven 4-wave barrier groups (r2: small blocks beat wide ones).
// All accumulation/softmax/LN stay f32; only matmul INPUTS are f16.
__global__ __launch_bounds__(NT, 8) void attn_fused(
    const float* __restrict__ x, const float* __restrict__ mask,
    const float* __restrict__ Wq, const float* __restrict__ bq,
    const float* __restrict__ Wk, const float* __restrict__ bk,
    const float* __restrict__ Wv, const float* __restrict__ bv,
    const float* __restrict__ gamma, const float* __restrict__ beta,
    float* __restrict__ out, int B) {
  __shared__ __align__(16) __fp16 sWh[3][4][KVD][16];  // 3456 B (half9 zeroed, 10..15 unread)
  __shared__ __align__(16) float  sBias[3][4][12];     //  576 B
  __shared__ __align__(16) float  sMsk[28];            //  112 B (mask*MSCALE, score seeds)
  __shared__ __align__(16) __fp16 sKh[IPB][NQ][16];    // 8000 B (K rows, f16, 32B stride)
  __shared__ __align__(16) __fp16 sVT[IPB][KVD][32];   // 5760 B (V transposed, f16, 64B rows)

  const int tid = threadIdx.x;
  const int il = tid / NQ;
  const int tk = tid - il * NQ;
  const long item = (long)blockIdx.x * IPB + il;
  const bool active = (tid < IPB * NQ) && (item < (long)B);

  // ---- prefetch x (f32 kept for residual) ----
  float xv[KVD];
  if (active) {
    const float* xp = x + item * 225 + tk * KVD;
#pragma unroll
    for (int d = 0; d < KVD; ++d) xv[d] = xp[d];
  }

  // ---- stage weights as f16 (Wq pre-scaled by log2e/3), biases f32 ----
  for (int i = tid; i < 324; i += NT) {  // 4*9*9
    int g = i / 81;
    int r = i - g * 81;
    int e = r / 9;
    int d = r - e * 9;
    float a = Wq[i] * QSCALE, b = Wk[i], c = Wv[i];
    if (d == 8) {  // write halves 8,9 as one b32 {w8, 0} -> zero pad deterministic
      *(h2*)&sWh[0][g][e][8] = pk(a, 0.f);
      *(h2*)&sWh[1][g][e][8] = pk(b, 0.f);
      *(h2*)&sWh[2][g][e][8] = pk(c, 0.f);
    } else {
      sWh[0][g][e][d] = (__fp16)a;
      sWh[1][g][e][d] = (__fp16)b;
      sWh[2][g][e][d] = (__fp16)c;
    }
  }
  if (tid < 36) {
    int g = tid / 9, d = tid - g * 9;
    sBias[0][g][d] = bq[tid] * QSCALE;
    sBias[1][g][d] = bk[tid];
    sBias[2][g][d] = bv[tid];
  }
  if (tid < NQ) sMsk[tid] = mask[tid] * MSCALE;
  __syncthreads();

  const int g = (tk < 3) ? 0 : (tk < 13) ? 1 : (tk < 23) ? 2 : 3;
  h2 xh[5];
  if (active) {
    xh[0] = pk(xv[0], xv[1]); xh[1] = pk(xv[2], xv[3]);
    xh[2] = pk(xv[4], xv[5]); xh[3] = pk(xv[6], xv[7]);
    xh[4] = pk(xv[8], 0.f);

    float t[KVD];
    // K projection -> f16 row (5 h2 stores, merged by compiler)
    proj9h(&sWh[1][g][0][0], &sBias[1][g][0], xh, t);
    h2* kr = (h2*)&sKh[il][tk][0];
    kr[0] = pk(t[0], t[1]); kr[1] = pk(t[2], t[3]); kr[2] = pk(t[4], t[5]);
    kr[3] = pk(t[6], t[7]); kr[4] = pk(t[8], 0.f);
    // V projection -> transposed f16 (per-d scalar stores; tk==24 also zeroes
    // half 25 via a pair store so the PV tail pair never multiplies garbage)
    proj9h(&sWh[2][g][0][0], &sBias[2][g][0], xh, t);
    if (tk == 24) {
#pragma unroll
      for (int d = 0; d < KVD; ++d) *(h2*)&sVT[il][d][24] = pk(t[d], 0.f);
    } else {
#pragma unroll
      for (int d = 0; d < KVD; ++d) sVT[il][d][tk] = (__fp16)t[d];
    }
  }
  __syncthreads();

  if (active) {
    // Q projection after the barrier (short live ranges), then to f16 pairs
    float qf[KVD];
    proj9h(&sWh[0][g][0][0], &sBias[0][g][0], xh, qf);
    h2 qh[5];
    qh[0] = pk(qf[0], qf[1]); qh[1] = pk(qf[2], qf[3]);
    qh[2] = pk(qf[4], qf[5]); qh[3] = pk(qf[6], qf[7]);
    qh[4] = pk(qf[8], 0.f);

    // ---- scores: seed with precomputed mask*MSCALE, 5 fdot2 per key ----
    float s[NQ];
#pragma unroll
    for (int j = 0; j < NQ; ++j) s[j] = sMsk[j];
#pragma unroll
    for (int j = 0; j < NQ; ++j) {
      const h2* krj = (const h2*)&sKh[il][j][0];
      float a = s[j];
#pragma unroll
      for (int t = 0; t < 5; ++t) a = fdot2(krj[t], qh[t], a);
      s[j] = a;
    }

    // ---- max: v_max3-friendly tree, dep depth 3 ----
    float t0 = fmaxf(fmaxf(s[0], s[1]), s[2]);
    float t1 = fmaxf(fmaxf(s[3], s[4]), s[5]);
    float t2 = fmaxf(fmaxf(s[6], s[7]), s[8]);
    float t3 = fmaxf(fmaxf(s[9], s[10]), s[11]);
    float t4 = fmaxf(fmaxf(s[12], s[13]), s[14]);
    float t5 = fmaxf(fmaxf(s[15], s[16]), s[17]);
    float t6 = fmaxf(fmaxf(s[18], s[19]), s[20]);
    float t7 = fmaxf(fmaxf(s[21], s[22]), s[23]);
    float u0 = fmaxf(fmaxf(t0, t1), t2);
    float u1 = fmaxf(fmaxf(t3, t4), t5);
    float u2 = fmaxf(fmaxf(t6, t7), s[24]);
    const float m = fmaxf(fmaxf(u0, u1), u2);

    // ---- exp2 + 4-chain sum (f32) ----
    float a0 = 0.f, a1 = 0.f, a2 = 0.f, a3 = 0.f;
#pragma unroll
    for (int j = 0; j < 24; j += 4) {
      float p0 = __builtin_amdgcn_exp2f(s[j + 0] - m);
      float p1 = __builtin_amdgcn_exp2f(s[j + 1] - m);
      float p2 = __builtin_amdgcn_exp2f(s[j + 2] - m);
      float p3 = __builtin_amdgcn_exp2f(s[j + 3] - m);
      s[j + 0] = p0; s[j + 1] = p1; s[j + 2] = p2; s[j + 3] = p3;
      a0 += p0; a1 += p1; a2 += p2; a3 += p3;
    }
    float p24 = __builtin_amdgcn_exp2f(s[24] - m);
    s[24] = p24;
    const float sum = ((a0 + a1) + (a2 + a3)) + p24;
    const float inv = __builtin_amdgcn_rcpf(sum);

    // ---- PV: weights to f16 pairs, dot2 over j against transposed V ----
    h2 ph[13];
#pragma unroll
    for (int t = 0; t < 12; ++t) ph[t] = pk(s[2 * t], s[2 * t + 1]);
    ph[12] = pk(s[24], 0.f);

    float o[KVD];
#pragma unroll
    for (int d = 0; d < KVD; ++d) {
      const h2* vr = (const h2*)&sVT[il][d][0];
      float a = 0.f;
#pragma unroll
      for (int t = 0; t < 13; ++t) a = fdot2(vr[t], ph[t], a);
      o[d] = a;
    }

    // ---- residual + one-pass LayerNorm (inv folded into residual fmaf) ----
    float r[KVD];
    float sm = 0.f, sq = 0.f;
#pragma unroll
    for (int d = 0; d < KVD; ++d) {
      r[d] = fmaf(o[d], inv, xv[d]);
      sm += r[d];
      sq = fmaf(r[d], r[d], sq);
    }
    const float mu = sm * (1.0f / 9.0f);
    float var = fmaf(mu, -mu, sq * (1.0f / 9.0f));
    const float rs = __builtin_amdgcn_rsqf(var + 1e-5f);
    float* op = out + item * 225 + tk * KVD;
    // gamma/beta: wave-uniform s_loads
#pragma unroll
    for (int d = 0; d < KVD; ++d)
      op[d] = fmaf((r[d] - mu) * rs, gamma[d], beta[d]);
  }
}

extern "C" void kernel_launch(void* const* d_in, const int* in_sizes, int n_in,
                              void* d_out, int out_size, void* d_ws, size_t ws_size,
                              hipStream_t stream) {
  const float* x     = (const float*)d_in[0];
  const float* mask  = (const float*)d_in[1];
  const float* Wq    = (const float*)d_in[2];
  const float* bq    = (const float*)d_in[3];
  const float* Wk    = (const float*)d_in[4];
  const float* bk    = (const float*)d_in[5];
  const float* Wv    = (const float*)d_in[6];
  const float* bv    = (const float*)d_in[7];
  const float* gamma = (const float*)d_in[8];
  const float* beta  = (const float*)d_in[9];
  float* out = (float*)d_out;
  const int B = in_sizes[0] / 225;
  const int grid = (B + IPB - 1) / IPB;
  attn_fused<<<grid, NT, 0, stream>>>(x, mask, Wq, bq, Wk, bk, Wv, bv,
                                      gamma, beta, out, B);
}